// Round 5
// baseline (137.431 us; speedup 1.0000x reference)
//
#include <hip/hip_runtime.h>

#define NCH 32          // channels
#define GROUPS 8        // float4 groups per row (32 / 4)
#define KVOL 27         // 3^3 kernel offsets
#define LG 100          // grid side
#define LP 102          // padded side (1-cell zero ring)
#define RGN 5           // region side per block
#define NRGN 20         // LG / RGN
#define NREGIONS (NRGN * NRGN * NRGN)   // 8000
#define BSIDE 7         // RGN + 2
#define BVOL 343        // brick cells
#define CELLS 125       // RGN^3
#define LSTR 28         // uint taps per row (112B stride, 16B-aligned)

// ---- Kernel 1: padded dense presence map: dense[flatp] = row+1 --------------
__global__ void build_dense(const int* __restrict__ coords,
                            int* __restrict__ dense, int N) {
    int i = blockIdx.x * blockDim.x + threadIdx.x;
    if (i >= N) return;
    int x = coords[3 * i + 0];
    int y = coords[3 * i + 1];
    int z = coords[3 * i + 2];
    dense[((size_t)(x + 1) * LP + (y + 1)) * LP + (z + 1)] = i + 1;
}

// ---- Kernel 2: region gather ------------------------------------------------
// LDS 20KB + VGPR<=64 -> 8 blocks/CU. kw rows at 128B stride: octet-g b128
// reads cover banks 4g..4g+3 uniformly -> conflict-free. Tap entries are uint
// (row<<13 | k<<7). Lists padded to a multiple of 8 taps; gather runs 2
// quad-steps per iteration = 8 independent feat loads in flight per octet.
__global__ __launch_bounds__(256, 8) void gather_conv_region(
        const int* __restrict__ dense,
        const float4* __restrict__ in_feats4,
        const float4* __restrict__ kernel4,
        float4* __restrict__ out4) {
    __shared__ float4 kw[(KVOL + 1) * GROUPS];      // 3584 B (row 27 = zeros)
    __shared__ int brick[BVOL];                     // row+1 (0 = empty) 1372 B
    __shared__ int qmeta[CELLS];                    // cell | nq<<9 | rank<<12
    __shared__ int smap[CELLS];                     // sorted -> (q<<4)|nq
    __shared__ int hist[7];
    __shared__ __align__(16) unsigned int list[CELLS * LSTR]; // 14000 B
    __shared__ int nint;

    int tid = threadIdx.x;
    int g   = tid & 7;

    if (tid == 0) nint = 0;
    if (tid < 7) hist[tid] = 0;
    if (tid < (KVOL + 1) * GROUPS) {
        int kr = tid >> 3;
        kw[tid] = (kr < KVOL) ? kernel4[tid]
                              : make_float4(0.f, 0.f, 0.f, 0.f);
    }

    // XCD slab swizzle (8000 % 8 == 0 -> bijective)
    int b = blockIdx.x;
    int r = (b & 7) * (NREGIONS >> 3) + (b >> 3);
    int bx = r / (NRGN * NRGN);
    int by = (r / NRGN) % NRGN;
    int bz = r % NRGN;
    int ox = bx * RGN, oy = by * RGN, oz = bz * RGN;

    // Brick load + interior queue (dense map pre-zeroed; L2-hot, 4.25 MB).
    for (int i = tid; i < BVOL; i += 256) {
        int lx = i / 49, ly = (i / 7) % 7, lz = i % 7;
        int v = dense[((size_t)(ox + lx) * LP + (oy + ly)) * LP + (oz + lz)];
        brick[i] = v;
        if (v && (unsigned)(lx - 1) < RGN && (unsigned)(ly - 1) < RGN &&
            (unsigned)(lz - 1) < RGN) {
            int p = atomicAdd(&nint, 1);
            qmeta[p] = i;                            // cell in bits 0..8
        }
    }
    __syncthreads();

    int n = nint;

    // Fill: one octet per queued cell; lanes cover k = l, l+8, l+16, l+24.
    // Positions via ballot-prefix within the octet -> no atomics, dword writes.
    int oct = tid >> 3, l = tid & 7;
    int rounds = (n + 31) >> 5;                      // block-uniform
    for (int rd = 0; rd < rounds; ++rd) {
        int q = (rd << 5) + oct;
        bool valid = q < n;
        int cell = valid ? (qmeta[q] & 511) : 0;
        int cnt = 0;
        unsigned base = (unsigned)q * LSTR;
        #pragma unroll
        for (int s = 0; s < 4; ++s) {
            int k = l + (s << 3);
            int nb = 0;
            if (valid && k < KVOL) {
                int off = (k / 9) * 49 + ((k / 3) % 3) * 7 + (k % 3) - 57;
                nb = brick[cell + off];
            }
            unsigned long long bal = __ballot(nb > 0);
            int byte = (int)((bal >> ((oct & 7) << 3)) & 0xFF);
            if (nb > 0) {
                int pos = cnt + __popc(byte & ((1 << l) - 1));
                list[base + pos] =
                    ((unsigned)(nb - 1) << 13) | ((unsigned)k << 7);
            }
            cnt += __popc(byte);
        }
        if (valid && l == 0) {
            int j = cnt;                             // >=1 (center tap)
            unsigned dummy =
                ((unsigned)(brick[cell] - 1) << 13) | (27u << 7);
            // pad to a multiple of 8 taps (2 quads), cap at 28 (nq=7 odd ->
            // handled by gather epilogue; needs >=25 real taps, ultra-rare)
            while ((j & 7) && j < 28) list[base + (j++)] = dummy;
            int nq = j >> 2;                         // 2,4,6 (or 7)
            int h = atomicAdd(&hist[nq - 1], 1);
            qmeta[q] = cell | (nq << 9) | (h << 12);
        }
    }
    __syncthreads();

    // Placement: descending tap count -> octets in a wave get equal trips.
    if (tid < n) {
        int m  = qmeta[tid];
        int nq = (m >> 9) & 7;
        int pos = m >> 12;
        #pragma unroll
        for (int bb = 1; bb < 7; ++bb)
            if (bb >= nq) pos += hist[bb];
        smap[pos] = (tid << 4) | nq;
    }
    __syncthreads();

    // Gather: octet per row; 2 quad-steps per iteration -> 8 independent
    // feat loads in flight. kw b128 reads conflict-free by 128B stride.
    const char* kwb = (const char*)kw + (g << 4);
    int lr = tid >> 3;
    for (int base = 0; base < n; base += 32) {
        int lo = base + lr;
        if (lo < n) {
            int d    = smap[lo];
            int q    = d >> 4;
            int nq   = d & 15;
            int orow = brick[qmeta[q] & 511] - 1;
            const uint4* tl = (const uint4*)&list[(unsigned)q * LSTR];
            float4 acc = make_float4(0.f, 0.f, 0.f, 0.f);
            int npair = nq >> 1;
            for (int jp = 0; jp < npair; ++jp) {
                uint4 A = tl[2 * jp + 0];
                uint4 B = tl[2 * jp + 1];
                float4 fa0 = in_feats4[(size_t)(A.x >> 13) * GROUPS + g];
                float4 fa1 = in_feats4[(size_t)(A.y >> 13) * GROUPS + g];
                float4 fa2 = in_feats4[(size_t)(A.z >> 13) * GROUPS + g];
                float4 fa3 = in_feats4[(size_t)(A.w >> 13) * GROUPS + g];
                float4 fb0 = in_feats4[(size_t)(B.x >> 13) * GROUPS + g];
                float4 fb1 = in_feats4[(size_t)(B.y >> 13) * GROUPS + g];
                float4 fb2 = in_feats4[(size_t)(B.z >> 13) * GROUPS + g];
                float4 fb3 = in_feats4[(size_t)(B.w >> 13) * GROUPS + g];
                float4 wa0 = *(const float4*)(kwb + (A.x & 0x1F80u));
                float4 wa1 = *(const float4*)(kwb + (A.y & 0x1F80u));
                float4 wa2 = *(const float4*)(kwb + (A.z & 0x1F80u));
                float4 wa3 = *(const float4*)(kwb + (A.w & 0x1F80u));
                float4 wb0 = *(const float4*)(kwb + (B.x & 0x1F80u));
                float4 wb1 = *(const float4*)(kwb + (B.y & 0x1F80u));
                float4 wb2 = *(const float4*)(kwb + (B.z & 0x1F80u));
                float4 wb3 = *(const float4*)(kwb + (B.w & 0x1F80u));
                acc.x += fa0.x * wa0.x; acc.y += fa0.y * wa0.y;
                acc.z += fa0.z * wa0.z; acc.w += fa0.w * wa0.w;
                acc.x += fa1.x * wa1.x; acc.y += fa1.y * wa1.y;
                acc.z += fa1.z * wa1.z; acc.w += fa1.w * wa1.w;
                acc.x += fa2.x * wa2.x; acc.y += fa2.y * wa2.y;
                acc.z += fa2.z * wa2.z; acc.w += fa2.w * wa2.w;
                acc.x += fa3.x * wa3.x; acc.y += fa3.y * wa3.y;
                acc.z += fa3.z * wa3.z; acc.w += fa3.w * wa3.w;
                acc.x += fb0.x * wb0.x; acc.y += fb0.y * wb0.y;
                acc.z += fb0.z * wb0.z; acc.w += fb0.w * wb0.w;
                acc.x += fb1.x * wb1.x; acc.y += fb1.y * wb1.y;
                acc.z += fb1.z * wb1.z; acc.w += fb1.w * wb1.w;
                acc.x += fb2.x * wb2.x; acc.y += fb2.y * wb2.y;
                acc.z += fb2.z * wb2.z; acc.w += fb2.w * wb2.w;
                acc.x += fb3.x * wb3.x; acc.y += fb3.y * wb3.y;
                acc.z += fb3.z * wb3.z; acc.w += fb3.w * wb3.w;
            }
            if (nq & 1) {                            // nq==7 epilogue (rare)
                uint4 L = tl[nq - 1];
                float4 f0 = in_feats4[(size_t)(L.x >> 13) * GROUPS + g];
                float4 f1 = in_feats4[(size_t)(L.y >> 13) * GROUPS + g];
                float4 f2 = in_feats4[(size_t)(L.z >> 13) * GROUPS + g];
                float4 f3 = in_feats4[(size_t)(L.w >> 13) * GROUPS + g];
                float4 w0 = *(const float4*)(kwb + (L.x & 0x1F80u));
                float4 w1 = *(const float4*)(kwb + (L.y & 0x1F80u));
                float4 w2 = *(const float4*)(kwb + (L.z & 0x1F80u));
                float4 w3 = *(const float4*)(kwb + (L.w & 0x1F80u));
                acc.x += f0.x * w0.x; acc.y += f0.y * w0.y;
                acc.z += f0.z * w0.z; acc.w += f0.w * w0.w;
                acc.x += f1.x * w1.x; acc.y += f1.y * w1.y;
                acc.z += f1.z * w1.z; acc.w += f1.w * w1.w;
                acc.x += f2.x * w2.x; acc.y += f2.y * w2.y;
                acc.z += f2.z * w2.z; acc.w += f2.w * w2.w;
                acc.x += f3.x * w3.x; acc.y += f3.y * w3.y;
                acc.z += f3.z * w3.z; acc.w += f3.w * w3.w;
            }
            out4[(size_t)orow * GROUPS + g] = acc;
        }
    }
}

// ---- Fallback (atomic scatter) if ws is too small ---------------------------
__global__ void mink_conv_scatter(const int* __restrict__ coords,
                                  const int* __restrict__ in_idx,
                                  const int* __restrict__ out_idx,
                                  const float4* __restrict__ in_feats4,
                                  const float4* __restrict__ kernel4,
                                  float* __restrict__ out,
                                  int E) {
    __shared__ float4 kws[KVOL * GROUPS];
    for (int i = threadIdx.x; i < KVOL * GROUPS; i += blockDim.x)
        kws[i] = kernel4[i];
    __syncthreads();
    int t = blockIdx.x * blockDim.x + threadIdx.x;
    if (t >= E * GROUPS) return;
    int e = t >> 3, g = t & 7;
    int vi = in_idx[e], vo = out_idx[e];
    int c0 = coords[vi * 3 + 0] - coords[vo * 3 + 0] + 1;
    int c1 = coords[vi * 3 + 1] - coords[vo * 3 + 1] + 1;
    int c2 = coords[vi * 3 + 2] - coords[vo * 3 + 2] + 1;
    int k1d = (c0 * 3 + c1) * 3 + c2;
    float4 f = in_feats4[vi * GROUPS + g];
    float4 w = kws[k1d * GROUPS + g];
    float* o = out + vo * NCH + g * 4;
    atomicAdd(o + 0, f.x * w.x);
    atomicAdd(o + 1, f.y * w.y);
    atomicAdd(o + 2, f.z * w.z);
    atomicAdd(o + 3, f.w * w.w);
}

extern "C" void kernel_launch(void* const* d_in, const int* in_sizes, int n_in,
                              void* d_out, int out_size, void* d_ws, size_t ws_size,
                              hipStream_t stream) {
    const int*   coords   = (const int*)d_in[0];
    const int*   in_idx   = (const int*)d_in[1];
    const int*   out_idx  = (const int*)d_in[2];
    const float* in_feats = (const float*)d_in[3];
    const float* kernel   = (const float*)d_in[4];

    const int E     = in_sizes[1];
    const int Nrows = out_size / NCH;

    const size_t dense_bytes = (size_t)LP * LP * LP * sizeof(int); // 4.25 MB

    if (ws_size >= dense_bytes) {
        int* dense = (int*)d_ws;
        hipMemsetAsync(dense, 0, dense_bytes, stream);

        int block = 256;
        int grid1 = (Nrows + block - 1) / block;
        build_dense<<<grid1, block, 0, stream>>>(coords, dense, Nrows);

        gather_conv_region<<<NREGIONS, 256, 0, stream>>>(
            dense, (const float4*)in_feats, (const float4*)kernel,
            (float4*)d_out);
    } else {
        hipMemsetAsync(d_out, 0, (size_t)out_size * sizeof(float), stream);
        int total = E * GROUPS;
        int block = 256;
        int grid  = (total + block - 1) / block;
        mink_conv_scatter<<<grid, block, 0, stream>>>(
            coords, in_idx, out_idx,
            (const float4*)in_feats, (const float4*)kernel,
            (float*)d_out, E);
    }
}

// Round 6
// 136.621 us; speedup vs baseline: 1.0059x; 1.0059x over previous
//
#include <hip/hip_runtime.h>

#define NCH 32          // channels
#define GROUPS 8        // float4 groups per row (32 / 4)
#define KVOL 27         // 3^3 kernel offsets
#define LG 100          // grid side
#define LP 102          // padded side (1-cell zero ring)
#define RGN 5           // region side per block
#define NRGN 20         // LG / RGN
#define NREGIONS (NRGN * NRGN * NRGN)   // 8000
#define BSIDE 7         // RGN + 2
#define BVOL 343        // brick cells
#define CELLS 125       // RGN^3

// ---- Kernel 1: padded dense presence map: dense[flatp] = row+1 --------------
__global__ void build_dense(const int* __restrict__ coords,
                            int* __restrict__ dense, int N) {
    int i = blockIdx.x * blockDim.x + threadIdx.x;
    if (i >= N) return;
    int x = coords[3 * i + 0];
    int y = coords[3 * i + 1];
    int z = coords[3 * i + 2];
    dense[((size_t)(x + 1) * LP + (y + 1)) * LP + (z + 1)] = i + 1;
}

// ---- Kernel 2: region gather, bitmask taps ----------------------------------
// No per-cell tap lists: occupied cells OR a bit into a per-(x,y) column
// z-mask during the brick load; each output cell derives its 27-bit tap mask
// from 9 column reads. Gather extracts 4 taps/step via ctz + koff LUT
// (packed brick-offset | kw byte-offset; entry 27 = dummy -> own row, zero
// weights). Rows count-sorted by popcount, wave-interleaved placement.
// LDS ~6.8 KB; kw rows at 128B stride (bank-uniform b128 reads).
__global__ __launch_bounds__(256, 8) void gather_conv_region(
        const int* __restrict__ dense,
        const float4* __restrict__ in_feats4,
        const float4* __restrict__ kernel4,
        float4* __restrict__ out4) {
    __shared__ float4 kw[(KVOL + 1) * GROUPS];  // 3584 B (row 27 = zeros)
    __shared__ int brick[BVOL];                 // row+1 (0 = empty)
    __shared__ unsigned bitcol[49];             // per-(x,y) column z-bits
    __shared__ int qmeta[CELLS];                // coords|cell<<9|nb<<18|h<<22
    __shared__ unsigned qmask[CELLS];           // 27-bit tap mask
    __shared__ int smap[CELLS];                 // sorted slot -> (q<<5)|nb
    __shared__ unsigned koff[KVOL + 1];         // (k*128)<<7 | brickoff
    __shared__ int hist[7];
    __shared__ int nint;

    int tid = threadIdx.x;
    int g   = tid & 7;

    if (tid == 0) nint = 0;
    if (tid < 7) hist[tid] = 0;
    if (tid < 49) bitcol[tid] = 0;
    if (tid < KVOL + 1) {
        int k = tid;
        int dx = 1, dy = 1, dz = 1;              // k=27 dummy -> center cell
        if (k < KVOL) { dx = k / 9; dy = (k / 3) % 3; dz = k % 3; }
        int off = dx * 49 + dy * 7 + dz;         // 0..114, center = 57
        koff[tid] = ((unsigned)(k * 128) << 7) | (unsigned)off;
    }
    if (tid < (KVOL + 1) * GROUPS) {
        int kr = tid >> 3;
        kw[tid] = (kr < KVOL) ? kernel4[tid]
                              : make_float4(0.f, 0.f, 0.f, 0.f);
    }

    // XCD slab swizzle (8000 % 8 == 0 -> bijective)
    int b = blockIdx.x;
    int r = (b & 7) * (NREGIONS >> 3) + (b >> 3);
    int bx = r / (NRGN * NRGN);
    int by = (r / NRGN) % NRGN;
    int bz = r % NRGN;
    int ox = bx * RGN, oy = by * RGN, oz = bz * RGN;

    // Brick load + column-bit OR + interior queue (dense pre-zeroed, L2-hot).
    for (int i = tid; i < BVOL; i += 256) {
        int lx = i / 49, ly = (i / 7) % 7, lz = i % 7;
        int v = dense[((size_t)(ox + lx) * LP + (oy + ly)) * LP + (oz + lz)];
        brick[i] = v;
        if (v) {
            atomicOr(&bitcol[lx * 7 + ly], 1u << lz);
            if ((unsigned)(lx - 1) < RGN && (unsigned)(ly - 1) < RGN &&
                (unsigned)(lz - 1) < RGN) {
                int p = atomicAdd(&nint, 1);
                qmeta[p] = lx | (ly << 3) | (lz << 6) | (i << 9);
            }
        }
    }
    __syncthreads();

    int n = nint;

    // 27-bit tap mask per queued cell: 9 column reads, 3 z-bits each.
    if (tid < n) {
        int m0 = qmeta[tid];
        int lx = m0 & 7, ly = (m0 >> 3) & 7, lz = (m0 >> 6) & 7;
        int colbase = (lx - 1) * 7 + (ly - 1);
        unsigned mask = 0;
        #pragma unroll
        for (int dx = 0; dx < 3; ++dx)
            #pragma unroll
            for (int dy = 0; dy < 3; ++dy) {
                unsigned c = (bitcol[colbase + dx * 7 + dy] >> (lz - 1)) & 7u;
                mask |= c << (dx * 9 + dy * 3);
            }
        qmask[tid] = mask;
        int nb = (__popc(mask) + 3) >> 2;        // quad batches, 1..7
        int h = atomicAdd(&hist[nb - 1], 1);
        qmeta[tid] = m0 | (nb << 18) | (h << 22);
    }
    __syncthreads();

    // Placement: descending batch count; within full 32-buckets interleave
    // ranks across waves (rank r -> octet 8*(r&3) + ((r>>2)&7)).
    if (tid < n) {
        int m0 = qmeta[tid];
        int nb = (m0 >> 18) & 15;
        int pos = m0 >> 22;
        #pragma unroll
        for (int bb = 1; bb < 7; ++bb)
            if (bb >= nb) pos += hist[bb];
        int s = pos;
        if (pos < (n & ~31))
            s = (pos & ~31) | ((pos >> 2) & 7) | ((pos & 3) << 3);
        smap[s] = (tid << 5) | nb;
    }
    __syncthreads();

    // Gather: octet per row; 4 taps/step = ctz+koff -> brick row -> feat/kw.
    const char* kwb = (const char*)kw + (g << 4);
    int lr = tid >> 3;
    for (int base = 0; base < n; base += 32) {
        int lo = base + lr;
        if (lo < n) {
            int d     = smap[lo];
            int q     = d >> 5;
            int nb    = d & 31;
            int m0    = qmeta[q];
            int cell  = (m0 >> 9) & 511;
            int cellb = cell - 57;
            int orow  = brick[cell] - 1;
            unsigned m = qmask[q];
            float4 acc = make_float4(0.f, 0.f, 0.f, 0.f);
            for (int t = 0; t < nb; ++t) {
                int k0 = m ? __builtin_ctz(m) : KVOL; m &= m - 1;
                int k1 = m ? __builtin_ctz(m) : KVOL; m &= m - 1;
                int k2 = m ? __builtin_ctz(m) : KVOL; m &= m - 1;
                int k3 = m ? __builtin_ctz(m) : KVOL; m &= m - 1;
                unsigned o0 = koff[k0], o1 = koff[k1];
                unsigned o2 = koff[k2], o3 = koff[k3];
                int v0 = brick[cellb + (int)(o0 & 127u)];
                int v1 = brick[cellb + (int)(o1 & 127u)];
                int v2 = brick[cellb + (int)(o2 & 127u)];
                int v3 = brick[cellb + (int)(o3 & 127u)];
                float4 f0 = in_feats4[(size_t)(v0 - 1) * GROUPS + g];
                float4 f1 = in_feats4[(size_t)(v1 - 1) * GROUPS + g];
                float4 f2 = in_feats4[(size_t)(v2 - 1) * GROUPS + g];
                float4 f3 = in_feats4[(size_t)(v3 - 1) * GROUPS + g];
                float4 w0 = *(const float4*)(kwb + (o0 >> 7));
                float4 w1 = *(const float4*)(kwb + (o1 >> 7));
                float4 w2 = *(const float4*)(kwb + (o2 >> 7));
                float4 w3 = *(const float4*)(kwb + (o3 >> 7));
                acc.x += f0.x * w0.x; acc.y += f0.y * w0.y;
                acc.z += f0.z * w0.z; acc.w += f0.w * w0.w;
                acc.x += f1.x * w1.x; acc.y += f1.y * w1.y;
                acc.z += f1.z * w1.z; acc.w += f1.w * w1.w;
                acc.x += f2.x * w2.x; acc.y += f2.y * w2.y;
                acc.z += f2.z * w2.z; acc.w += f2.w * w2.w;
                acc.x += f3.x * w3.x; acc.y += f3.y * w3.y;
                acc.z += f3.z * w3.z; acc.w += f3.w * w3.w;
            }
            out4[(size_t)orow * GROUPS + g] = acc;
        }
    }
}

// ---- Fallback (atomic scatter) if ws is too small ---------------------------
__global__ void mink_conv_scatter(const int* __restrict__ coords,
                                  const int* __restrict__ in_idx,
                                  const int* __restrict__ out_idx,
                                  const float4* __restrict__ in_feats4,
                                  const float4* __restrict__ kernel4,
                                  float* __restrict__ out,
                                  int E) {
    __shared__ float4 kws[KVOL * GROUPS];
    for (int i = threadIdx.x; i < KVOL * GROUPS; i += blockDim.x)
        kws[i] = kernel4[i];
    __syncthreads();
    int t = blockIdx.x * blockDim.x + threadIdx.x;
    if (t >= E * GROUPS) return;
    int e = t >> 3, g = t & 7;
    int vi = in_idx[e], vo = out_idx[e];
    int c0 = coords[vi * 3 + 0] - coords[vo * 3 + 0] + 1;
    int c1 = coords[vi * 3 + 1] - coords[vo * 3 + 1] + 1;
    int c2 = coords[vi * 3 + 2] - coords[vo * 3 + 2] + 1;
    int k1d = (c0 * 3 + c1) * 3 + c2;
    float4 f = in_feats4[vi * GROUPS + g];
    float4 w = kws[k1d * GROUPS + g];
    float* o = out + vo * NCH + g * 4;
    atomicAdd(o + 0, f.x * w.x);
    atomicAdd(o + 1, f.y * w.y);
    atomicAdd(o + 2, f.z * w.z);
    atomicAdd(o + 3, f.w * w.w);
}

extern "C" void kernel_launch(void* const* d_in, const int* in_sizes, int n_in,
                              void* d_out, int out_size, void* d_ws, size_t ws_size,
                              hipStream_t stream) {
    const int*   coords   = (const int*)d_in[0];
    const int*   in_idx   = (const int*)d_in[1];
    const int*   out_idx  = (const int*)d_in[2];
    const float* in_feats = (const float*)d_in[3];
    const float* kernel   = (const float*)d_in[4];

    const int E     = in_sizes[1];
    const int Nrows = out_size / NCH;

    const size_t dense_bytes = (size_t)LP * LP * LP * sizeof(int); // 4.25 MB

    if (ws_size >= dense_bytes) {
        int* dense = (int*)d_ws;
        hipMemsetAsync(dense, 0, dense_bytes, stream);

        int block = 256;
        int grid1 = (Nrows + block - 1) / block;
        build_dense<<<grid1, block, 0, stream>>>(coords, dense, Nrows);

        gather_conv_region<<<NREGIONS, 256, 0, stream>>>(
            dense, (const float4*)in_feats, (const float4*)kernel,
            (float4*)d_out);
    } else {
        hipMemsetAsync(d_out, 0, (size_t)out_size * sizeof(float), stream);
        int total = E * GROUPS;
        int block = 256;
        int grid  = (total + block - 1) / block;
        mink_conv_scatter<<<grid, block, 0, stream>>>(
            coords, in_idx, out_idx,
            (const float4*)in_feats, (const float4*)kernel,
            (float*)d_out, E);
    }
}